// Round 12
// baseline (85.957 us; speedup 1.0000x reference)
//
#include <hip/hip_runtime.h>
#include <math.h>

// ChamferLoss: target [B,M,2] f32, actual [B,N,2] f32
// out = concat(forward[B,M], backward[B,N]) f32
//
// Round 12: grid NN — flat 5x5 pass instead of expanding rings.
// Ring loop was serial: per-ring dependent CSR lookups -> gathers -> shfl
// -> check (91% latency stall, VALUBusy 9%). Now: 10 independent CSR range
// lookups issued upfront (5 contiguous row-spans of the 5x5 block), then
// streaming candidate evals. Exact: any point outside the 5x5 block is
// >= 3 cells away in x or y => d > 2*CELLW (clamp-safe: cell edges bound
// coords in the clamp direction). If best^2 > (2*CELLW)^2 (rare tail
// queries), wave-cooperative exact scan of the whole ref set (ballot +
// 64-lane coalesced stream + shfl reduce). Deterministic: both paths are
// exact mins over fixed multisets.

#define G     64
#define GG    (G * G)
#define CELLW 0.15625f      // 10/64
#define INVW  6.4f          // 64/10
#define NSETS 32            // 2 clouds * B
#define LG    4             // lanes per query

__device__ __forceinline__ int cell_of(float v) {
    int c = (int)floorf((v + 5.0f) * INVW);
    return c < 0 ? 0 : (c > G - 1 ? G - 1 : c);
}

// ---------- fused build: one block per set ----------
__global__ __launch_bounds__(256) void grid_build(
    const float2* __restrict__ tpts, const float2* __restrict__ apts,
    unsigned int* __restrict__ gstarts,  // [NSETS][GG+1]
    float2* __restrict__ spts,           // [NSETS][S]
    unsigned int* __restrict__ sidx,     // [NSETS][S]
    int M, int N, int B, int S)
{
    __shared__ unsigned int hist[GG];
    __shared__ unsigned int cur[GG];
    __shared__ unsigned int part[256];

    const int s = blockIdx.x;
    const int tid = threadIdx.x;
    const int cnt = (s < B) ? M : N;
    const float2* __restrict__ pts =
        (s < B) ? (tpts + (size_t)s * M) : (apts + (size_t)(s - B) * N);
    const unsigned int obase =
        (s < B) ? (unsigned)(s * M) : (unsigned)(B * M + (s - B) * N);

    for (int i = tid; i < GG; i += 256) hist[i] = 0u;
    __syncthreads();

    for (int i = tid; i < cnt; i += 256) {
        float2 p = pts[i];
        atomicAdd(&hist[cell_of(p.y) * G + cell_of(p.x)], 1u);
    }
    __syncthreads();

    unsigned int tmp[16], sum = 0;
    int base = tid * 16;
#pragma unroll
    for (int k = 0; k < 16; ++k) { tmp[k] = hist[base + k]; sum += tmp[k]; }
    part[tid] = sum;
    __syncthreads();
    for (int off = 1; off < 256; off <<= 1) {
        unsigned int v = (tid >= off) ? part[tid - off] : 0u;
        __syncthreads();
        part[tid] += v;
        __syncthreads();
    }
    unsigned int run = part[tid] - sum;   // exclusive prefix
    unsigned int* __restrict__ gs = gstarts + (size_t)s * (GG + 1);
#pragma unroll
    for (int k = 0; k < 16; ++k) {
        cur[base + k] = run;
        gs[base + k] = run;
        run += tmp[k];
    }
    if (tid == 255) gs[GG] = run;
    __syncthreads();

    for (int i = tid; i < cnt; i += 256) {
        float2 p = pts[i];
        int c = cell_of(p.y) * G + cell_of(p.x);
        unsigned int pos = atomicAdd(&cur[c], 1u);
        spts[(size_t)s * S + pos] = p;
        sidx[(size_t)s * S + pos] = obase + (unsigned)i;
    }
}

// ---------- query: flat 5x5 + cooperative fallback ----------
__global__ __launch_bounds__(256) void grid_query(
    const unsigned int* __restrict__ starts,
    const float2* __restrict__ spts,
    const unsigned int* __restrict__ sidx,
    float* __restrict__ out, int M, int N, int B, int S)
{
    const int s = blockIdx.y;
    const int cnt = (s < B) ? M : N;
    const int qpb = 256 / LG;
    int i = blockIdx.x * qpb + ((int)threadIdx.x / LG);
    const int sub  = (int)threadIdx.x & (LG - 1);
    const int lane = (int)threadIdx.x & 63;
    const bool valid = (i < cnt);
    if (i >= cnt) i = cnt - 1;          // clamp: keep all lanes resident

    float2 q = spts[(size_t)s * S + i];
    unsigned int oid = sidx[(size_t)s * S + i];
    const int rs = (s < B) ? (B + s) : (s - B);

    const unsigned int* __restrict__ st = starts + (size_t)rs * (GG + 1);
    const float2* __restrict__ rp = spts + (size_t)rs * S;

    const float qx = q.x, qy = q.y;
    const int cx = cell_of(qx), cy = cell_of(qy);
    int x0 = cx - 2; if (x0 < 0) x0 = 0;
    int x1 = cx + 2; if (x1 > G - 1) x1 = G - 1;

    // 5 contiguous row-spans; all 10 lookups independent -> one wait
    unsigned int j0s[5], j1s[5];
    int nr = 0;
#pragma unroll
    for (int dy = -2; dy <= 2; ++dy) {
        int yy = cy + dy;
        if ((unsigned)yy < (unsigned)G) {
            int rowb = yy * G;
            j0s[nr] = st[rowb + x0];
            j1s[nr] = st[rowb + x1 + 1];
            ++nr;
        }
    }

    float best = 3.0e38f;
    for (int rr = 0; rr < nr; ++rr) {
        for (unsigned int j = j0s[rr] + sub; j < j1s[rr]; j += LG) {
            float2 p = rp[j];
            float dx = qx - p.x, dy = qy - p.y;
            best = fminf(best, fmaf(dx, dx, dy * dy));
        }
    }
    // group consensus (LG=4)
    best = fminf(best, __shfl_xor(best, 1, 64));
    best = fminf(best, __shfl_xor(best, 2, 64));

    // rare fallback: exact whole-set scan, wave-cooperative
    const float thr2 = 4.0f * CELLW * CELLW;   // (2*CELLW)^2
    unsigned long long need = __ballot(valid && sub == 0 && best > thr2);
    if (need) {
        unsigned int rcount = st[GG];
        while (need) {
            int l = __ffsll((unsigned long long)need) - 1;
            float bqx = __shfl(qx, l, 64);
            float bqy = __shfl(qy, l, 64);
            float mb = 3.0e38f;
            for (unsigned int j = lane; j < rcount; j += 64) {
                float2 p = rp[j];
                float dx = bqx - p.x, dy = bqy - p.y;
                mb = fminf(mb, fmaf(dx, dx, dy * dy));
            }
#pragma unroll
            for (int o = 32; o; o >>= 1) mb = fminf(mb, __shfl_xor(mb, o, 64));
            if (lane == l) best = mb;
            need &= need - 1;
        }
    }

    if (valid && sub == 0) out[oid] = sqrtf(best);
}

// ---------------- fallback (round-5 proven brute force) ----------------
#define BLK 256
#define TM  8
#define RC  32

__device__ __forceinline__ float min3f(float a, float b, float c) {
    float d;
    asm("v_min3_f32 %0, %1, %2, %3" : "=v"(d) : "v"(a), "v"(b), "v"(c));
    return d;
}

__global__ __launch_bounds__(256) void chamfer_init(unsigned int* __restrict__ out, int n) {
    int i = blockIdx.x * 256 + threadIdx.x;
    if (i < n) out[i] = 0x7F800000u;
}

__global__ __launch_bounds__(BLK) void chamfer_partial(
    const float2* __restrict__ tpts, const float2* __restrict__ apts,
    unsigned int* __restrict__ out, int M, int N, int B)
{
    const int b = blockIdx.y, zc = blockIdx.z;
    const int dir = zc & 1, rc = zc >> 1;
    const float2* __restrict__ Q = dir ? apts : tpts;
    const float2* __restrict__ R = dir ? tpts : apts;
    const int NQ = dir ? N : M, NR = dir ? M : N;
    unsigned int* __restrict__ o =
        out + (dir ? ((size_t)B * M + (size_t)b * N) : ((size_t)b * M));
    const float2* __restrict__ q = Q + (size_t)b * NQ;
    const float2* __restrict__ r = R + (size_t)b * NR;
    const int clen = (NR + RC - 1) / RC;
    const int rbeg = rc * clen;
    const int rend = (rbeg + clen < NR) ? (rbeg + clen) : NR;
    if (rbeg >= rend) return;
    int qi[TM]; float n2x[TM], n2y[TM], qn[TM], mn[TM];
#pragma unroll
    for (int k = 0; k < TM; ++k) {
        qi[k] = blockIdx.x * (BLK * TM) + k * BLK + (int)threadIdx.x;
        int idx = qi[k] < NQ ? qi[k] : NQ - 1;
        float2 p = q[idx];
        n2x[k] = -2.0f * p.x; n2y[k] = -2.0f * p.y;
        qn[k] = fmaf(p.y, p.y, p.x * p.x); mn[k] = 3.0e38f;
    }
    int n = rbeg;
    for (; n + 8 <= rend; n += 8) {
        float vx[8], vy[8], va[8];
#pragma unroll
        for (int g = 0; g < 4; ++g) {
            float4 p4 = *(const float4*)&r[n + 2 * g];
            vx[2*g] = p4.x; vy[2*g] = p4.y; vx[2*g+1] = p4.z; vy[2*g+1] = p4.w;
            va[2*g]   = fmaf(p4.y, p4.y, p4.x * p4.x);
            va[2*g+1] = fmaf(p4.w, p4.w, p4.z * p4.z);
        }
#pragma unroll
        for (int k = 0; k < TM; ++k) {
            float v[8];
#pragma unroll
            for (int j = 0; j < 8; ++j)
                v[j] = fmaf(n2x[k], vx[j], fmaf(n2y[k], vy[j], va[j]));
            float m = min3f(v[0], v[1], v[2]);
            m = min3f(m, v[3], v[4]);
            m = min3f(m, v[5], v[6]);
            mn[k] = min3f(m, v[7], mn[k]);
        }
    }
    for (; n < rend; ++n) {
        float2 p = r[n];
        float va = fmaf(p.y, p.y, p.x * p.x);
#pragma unroll
        for (int k = 0; k < TM; ++k)
            mn[k] = fminf(mn[k], fmaf(n2x[k], p.x, fmaf(n2y[k], p.y, va)));
    }
#pragma unroll
    for (int k = 0; k < TM; ++k)
        if (qi[k] < NQ)
            atomicMin(&o[qi[k]], __float_as_uint(fmaxf(mn[k] + qn[k], 0.0f)));
}

__global__ __launch_bounds__(256) void chamfer_sqrt(unsigned int* __restrict__ io, int n) {
    int i = blockIdx.x * 256 + threadIdx.x;
    if (i < n) ((float*)io)[i] = sqrtf(__uint_as_float(io[i]));
}

// ---------------- launch ----------------
extern "C" void kernel_launch(void* const* d_in, const int* in_sizes, int n_in,
                              void* d_out, int out_size, void* d_ws, size_t ws_size,
                              hipStream_t stream) {
    const float2* tpts = (const float2*)d_in[0];
    const float2* apts = (const float2*)d_in[1];

    const int B = 16;
    const int M = in_sizes[0] / (B * 2);
    const int N = in_sizes[1] / (B * 2);
    const int S = M > N ? M : N;
    const int total = B * (M + N);

    // ws layout: starts | spts | sidx
    size_t starts_b = (size_t)NSETS * (GG + 1) * 4;
    size_t spts_b   = (size_t)NSETS * S * sizeof(float2);
    size_t sidx_b   = (size_t)NSETS * S * 4;
    size_t need = starts_b + spts_b + sidx_b;

    if (ws_size >= need) {
        unsigned int* starts = (unsigned int*)d_ws;
        float2* spts = (float2*)((char*)d_ws + starts_b);
        unsigned int* sidx = (unsigned int*)((char*)spts + spts_b);

        grid_build<<<NSETS, 256, 0, stream>>>(tpts, apts, starts, spts, sidx, M, N, B, S);
        const int qpb = 256 / LG;
        dim3 qgrid((S + qpb - 1) / qpb, NSETS);
        grid_query<<<qgrid, 256, 0, stream>>>(starts, spts, sidx,
                                              (float*)d_out, M, N, B, S);
    } else {
        unsigned int* out = (unsigned int*)d_out;
        chamfer_init<<<(total + 255) / 256, 256, 0, stream>>>(out, total);
        dim3 grid((S + BLK * TM - 1) / (BLK * TM), B, 2 * RC);
        chamfer_partial<<<grid, dim3(BLK), 0, stream>>>(tpts, apts, out, M, N, B);
        chamfer_sqrt<<<(total + 255) / 256, 256, 0, stream>>>(out, total);
    }
}

// Round 13
// 54.331 us; speedup vs baseline: 1.5821x; 1.5821x over previous
//
#include <hip/hip_runtime.h>
#include <math.h>

// ChamferLoss: target [B,M,2] f32, actual [B,N,2] f32
// out = concat(forward[B,M], backward[B,N]) f32
//
// Round 13: grid NN with the WHOLE ref set staged in LDS.
// Rounds 9-12 all died on serial dependent L2 gathers (VALUBusy 9-18%).
// One ref set = 4096 float2 = 32KB + CSR starts as u16 = 8KB -> 40KB LDS.
// Per block: stage once, then 128 sorted queries (LG=2 lanes each) do
// ring search entirely from LDS (span lookups ds_read_u16, candidates
// ds_read_b64; sorted queries => mostly broadcast reads). Flat 3x3 pass
// (bound CELLW^2) covers ~98% of queries; tail expands ring by ring from
// LDS — no whole-set fallback, no global gathers.
// Exact + deterministic: min over full fixed multiset, order-independent;
// ring-r stop bound (r*CELLW)^2 is clamp-safe (rounds 9-12 absmax=0.0).

#define G     64
#define GG    (G * G)
#define CELLW 0.15625f      // 10/64
#define INVW  6.4f          // 64/10
#define NSETS 32            // 2 clouds * B
#define LG    2             // lanes per query
#define MAXS  4096          // max points per set for LDS path

__device__ __forceinline__ int cell_of(float v) {
    int c = (int)floorf((v + 5.0f) * INVW);
    return c < 0 ? 0 : (c > G - 1 ? G - 1 : c);
}

// ---------- fused build: one block per set ----------
__global__ __launch_bounds__(256) void grid_build(
    const float2* __restrict__ tpts, const float2* __restrict__ apts,
    unsigned int* __restrict__ gstarts,  // [NSETS][GG+1]
    float2* __restrict__ spts,           // [NSETS][S]
    unsigned int* __restrict__ sidx,     // [NSETS][S]
    int M, int N, int B, int S)
{
    __shared__ unsigned int hist[GG];
    __shared__ unsigned int cur[GG];
    __shared__ unsigned int part[256];

    const int s = blockIdx.x;
    const int tid = threadIdx.x;
    const int cnt = (s < B) ? M : N;
    const float2* __restrict__ pts =
        (s < B) ? (tpts + (size_t)s * M) : (apts + (size_t)(s - B) * N);
    const unsigned int obase =
        (s < B) ? (unsigned)(s * M) : (unsigned)(B * M + (s - B) * N);

    for (int i = tid; i < GG; i += 256) hist[i] = 0u;
    __syncthreads();

    for (int i = tid; i < cnt; i += 256) {
        float2 p = pts[i];
        atomicAdd(&hist[cell_of(p.y) * G + cell_of(p.x)], 1u);
    }
    __syncthreads();

    unsigned int tmp[16], sum = 0;
    int base = tid * 16;
#pragma unroll
    for (int k = 0; k < 16; ++k) { tmp[k] = hist[base + k]; sum += tmp[k]; }
    part[tid] = sum;
    __syncthreads();
    for (int off = 1; off < 256; off <<= 1) {
        unsigned int v = (tid >= off) ? part[tid - off] : 0u;
        __syncthreads();
        part[tid] += v;
        __syncthreads();
    }
    unsigned int run = part[tid] - sum;   // exclusive prefix
    unsigned int* __restrict__ gs = gstarts + (size_t)s * (GG + 1);
#pragma unroll
    for (int k = 0; k < 16; ++k) {
        cur[base + k] = run;
        gs[base + k] = run;
        run += tmp[k];
    }
    if (tid == 255) gs[GG] = run;
    __syncthreads();

    for (int i = tid; i < cnt; i += 256) {
        float2 p = pts[i];
        int c = cell_of(p.y) * G + cell_of(p.x);
        unsigned int pos = atomicAdd(&cur[c], 1u);
        spts[(size_t)s * S + pos] = p;
        sidx[(size_t)s * S + pos] = obase + (unsigned)i;
    }
}

// ---------- query: whole ref set in LDS, per-lane ring search ----------
__global__ __launch_bounds__(256) void grid_query_lds(
    const unsigned int* __restrict__ starts,
    const float2* __restrict__ spts,
    const unsigned int* __restrict__ sidx,
    float* __restrict__ out, int M, int N, int B, int S)
{
    __shared__ float2 lp[MAXS];              // 32 KB
    __shared__ unsigned short lst[GG + 1];   // 8.2 KB

    const int s = blockIdx.y;
    const int cnt = (s < B) ? M : N;
    const int rs  = (s < B) ? (B + s) : (s - B);
    const int rcnt = (rs < B) ? M : N;
    const int tid = threadIdx.x;

    const unsigned int* __restrict__ gst = starts + (size_t)rs * (GG + 1);
    const float2* __restrict__ rp = spts + (size_t)rs * S;

    // stage starts as u16 (counts <= MAXS < 65536)
    for (int i = tid; i < GG + 1; i += 256) lst[i] = (unsigned short)gst[i];
    // stage ref points (float4 = 2 points per load)
    for (int i = tid; i * 2 < rcnt; i += 256)
        ((float4*)lp)[i] = ((const float4*)rp)[i];
    __syncthreads();

    const int qpb = 256 / LG;
    int i = blockIdx.x * qpb + (tid / LG);
    const int sub = tid & (LG - 1);
    const bool valid = (i < cnt);
    if (!valid) i = cnt - 1;

    float2 q = spts[(size_t)s * S + i];
    unsigned int oid = sidx[(size_t)s * S + i];
    const float qx = q.x, qy = q.y;
    const int cx = cell_of(qx), cy = cell_of(qy);

    float best = 3.0e38f;

    // flat 3x3 (rings 0..1): 3 contiguous row-spans
    {
        int x0 = cx - 1; if (x0 < 0) x0 = 0;
        int x1 = cx + 1; if (x1 > G - 1) x1 = G - 1;
#pragma unroll
        for (int dy = -1; dy <= 1; ++dy) {
            int yy = cy + dy;
            if ((unsigned)yy >= (unsigned)G) continue;
            int rowb = yy * G;
            unsigned int j0 = lst[rowb + x0], j1 = lst[rowb + x1 + 1];
            for (unsigned int j = j0 + sub; j < j1; j += LG) {
                float2 p = lp[j];
                float dx = qx - p.x, dyf = qy - p.y;
                best = fminf(best, fmaf(dx, dx, dyf * dyf));
            }
        }
    }
    best = fminf(best, __shfl_xor(best, 1, 64));   // LG=2 consensus

    // tail: expand rings from LDS
    if (best > CELLW * CELLW) {
        for (int r = 2; r <= G; ++r) {
            int x0 = cx - r; if (x0 < 0) x0 = 0;
            int x1 = cx + r; if (x1 > G - 1) x1 = G - 1;
#pragma unroll
            for (int e = 0; e < 2; ++e) {
                int yy = e ? cy + r : cy - r;
                if ((unsigned)yy >= (unsigned)G) continue;
                int rowb = yy * G;
                unsigned int j0 = lst[rowb + x0], j1 = lst[rowb + x1 + 1];
                for (unsigned int j = j0 + sub; j < j1; j += LG) {
                    float2 p = lp[j];
                    float dx = qx - p.x, dyf = qy - p.y;
                    best = fminf(best, fmaf(dx, dx, dyf * dyf));
                }
            }
            for (int dy = -(r - 1); dy <= r - 1; ++dy) {
                int yy = cy + dy;
                if ((unsigned)yy >= (unsigned)G) continue;
                int rowb = yy * G;
#pragma unroll
                for (int e = 0; e < 2; ++e) {
                    int xx = e ? cx + r : cx - r;
                    if ((unsigned)xx >= (unsigned)G) continue;
                    int c = rowb + xx;
                    unsigned int j0 = lst[c], j1 = lst[c + 1];
                    for (unsigned int j = j0 + sub; j < j1; j += LG) {
                        float2 p = lp[j];
                        float dxf = qx - p.x, dyf = qy - p.y;
                        best = fminf(best, fmaf(dxf, dxf, dyf * dyf));
                    }
                }
            }
            best = fminf(best, __shfl_xor(best, 1, 64));
            float bound = (float)r * CELLW;
            if (best <= bound * bound) break;
        }
    }

    if (valid && sub == 0) out[oid] = sqrtf(best);
}

// ---------------- fallback (round-5 proven brute force) ----------------
#define BLK 256
#define TM  8
#define RC  32

__device__ __forceinline__ float min3f(float a, float b, float c) {
    float d;
    asm("v_min3_f32 %0, %1, %2, %3" : "=v"(d) : "v"(a), "v"(b), "v"(c));
    return d;
}

__global__ __launch_bounds__(256) void chamfer_init(unsigned int* __restrict__ out, int n) {
    int i = blockIdx.x * 256 + threadIdx.x;
    if (i < n) out[i] = 0x7F800000u;
}

__global__ __launch_bounds__(BLK) void chamfer_partial(
    const float2* __restrict__ tpts, const float2* __restrict__ apts,
    unsigned int* __restrict__ out, int M, int N, int B)
{
    const int b = blockIdx.y, zc = blockIdx.z;
    const int dir = zc & 1, rc = zc >> 1;
    const float2* __restrict__ Q = dir ? apts : tpts;
    const float2* __restrict__ R = dir ? tpts : apts;
    const int NQ = dir ? N : M, NR = dir ? M : N;
    unsigned int* __restrict__ o =
        out + (dir ? ((size_t)B * M + (size_t)b * N) : ((size_t)b * M));
    const float2* __restrict__ q = Q + (size_t)b * NQ;
    const float2* __restrict__ r = R + (size_t)b * NR;
    const int clen = (NR + RC - 1) / RC;
    const int rbeg = rc * clen;
    const int rend = (rbeg + clen < NR) ? (rbeg + clen) : NR;
    if (rbeg >= rend) return;
    int qi[TM]; float n2x[TM], n2y[TM], qn[TM], mn[TM];
#pragma unroll
    for (int k = 0; k < TM; ++k) {
        qi[k] = blockIdx.x * (BLK * TM) + k * BLK + (int)threadIdx.x;
        int idx = qi[k] < NQ ? qi[k] : NQ - 1;
        float2 p = q[idx];
        n2x[k] = -2.0f * p.x; n2y[k] = -2.0f * p.y;
        qn[k] = fmaf(p.y, p.y, p.x * p.x); mn[k] = 3.0e38f;
    }
    int n = rbeg;
    for (; n + 8 <= rend; n += 8) {
        float vx[8], vy[8], va[8];
#pragma unroll
        for (int g = 0; g < 4; ++g) {
            float4 p4 = *(const float4*)&r[n + 2 * g];
            vx[2*g] = p4.x; vy[2*g] = p4.y; vx[2*g+1] = p4.z; vy[2*g+1] = p4.w;
            va[2*g]   = fmaf(p4.y, p4.y, p4.x * p4.x);
            va[2*g+1] = fmaf(p4.w, p4.w, p4.z * p4.z);
        }
#pragma unroll
        for (int k = 0; k < TM; ++k) {
            float v[8];
#pragma unroll
            for (int j = 0; j < 8; ++j)
                v[j] = fmaf(n2x[k], vx[j], fmaf(n2y[k], vy[j], va[j]));
            float m = min3f(v[0], v[1], v[2]);
            m = min3f(m, v[3], v[4]);
            m = min3f(m, v[5], v[6]);
            mn[k] = min3f(m, v[7], mn[k]);
        }
    }
    for (; n < rend; ++n) {
        float2 p = r[n];
        float va = fmaf(p.y, p.y, p.x * p.x);
#pragma unroll
        for (int k = 0; k < TM; ++k)
            mn[k] = fminf(mn[k], fmaf(n2x[k], p.x, fmaf(n2y[k], p.y, va)));
    }
#pragma unroll
    for (int k = 0; k < TM; ++k)
        if (qi[k] < NQ)
            atomicMin(&o[qi[k]], __float_as_uint(fmaxf(mn[k] + qn[k], 0.0f)));
}

__global__ __launch_bounds__(256) void chamfer_sqrt(unsigned int* __restrict__ io, int n) {
    int i = blockIdx.x * 256 + threadIdx.x;
    if (i < n) ((float*)io)[i] = sqrtf(__uint_as_float(io[i]));
}

// ---------------- launch ----------------
extern "C" void kernel_launch(void* const* d_in, const int* in_sizes, int n_in,
                              void* d_out, int out_size, void* d_ws, size_t ws_size,
                              hipStream_t stream) {
    const float2* tpts = (const float2*)d_in[0];
    const float2* apts = (const float2*)d_in[1];

    const int B = 16;
    const int M = in_sizes[0] / (B * 2);
    const int N = in_sizes[1] / (B * 2);
    const int S = M > N ? M : N;
    const int total = B * (M + N);

    // ws layout: starts | spts | sidx
    size_t starts_b = (size_t)NSETS * (GG + 1) * 4;
    size_t spts_b   = (size_t)NSETS * S * sizeof(float2);
    size_t sidx_b   = (size_t)NSETS * S * 4;
    size_t need = starts_b + spts_b + sidx_b;

    if (ws_size >= need && S <= MAXS && (M % 2 == 0) && (N % 2 == 0)) {
        unsigned int* starts = (unsigned int*)d_ws;
        float2* spts = (float2*)((char*)d_ws + starts_b);
        unsigned int* sidx = (unsigned int*)((char*)spts + spts_b);

        grid_build<<<NSETS, 256, 0, stream>>>(tpts, apts, starts, spts, sidx, M, N, B, S);
        const int qpb = 256 / LG;
        dim3 qgrid((S + qpb - 1) / qpb, NSETS);
        grid_query_lds<<<qgrid, 256, 0, stream>>>(starts, spts, sidx,
                                                  (float*)d_out, M, N, B, S);
    } else {
        unsigned int* out = (unsigned int*)d_out;
        chamfer_init<<<(total + 255) / 256, 256, 0, stream>>>(out, total);
        dim3 grid((S + BLK * TM - 1) / (BLK * TM), B, 2 * RC);
        chamfer_partial<<<grid, dim3(BLK), 0, stream>>>(tpts, apts, out, M, N, B);
        chamfer_sqrt<<<(total + 255) / 256, 256, 0, stream>>>(out, total);
    }
}